// Round 1
// baseline (4707.244 us; speedup 1.0000x reference)
//
#include <hip/hip_runtime.h>

#define HH 128
#define EPS 1e-5f

// ---------------- degree ----------------
__global__ void deg_kernel(const int* __restrict__ dst, float* __restrict__ deg, int E) {
    int e = blockIdx.x * 256 + threadIdx.x;
    if (e < E) atomicAdd(&deg[dst[e]], 1.0f);
}

__global__ void invdeg_kernel(float* __restrict__ deg, int N) {
    int n = blockIdx.x * 256 + threadIdx.x;
    if (n < N) deg[n] = 1.0f / fmaxf(deg[n], 1.0f);
}

// ---------------- edge scatter: agg[dst] += x[src] ----------------
__global__ void scatter_kernel(const float* __restrict__ x, const int* __restrict__ src,
                               const int* __restrict__ dst, float* __restrict__ agg, int E) {
    int idx = blockIdx.x * 256 + threadIdx.x;
    int e = idx >> 5;            // 32 threads (8 float4) per edge
    if (e >= E) return;
    int f4 = idx & 31;
    int s = src[e], d = dst[e];
    const float4 v = ((const float4*)(x + (size_t)s * HH))[f4];
    float* base = agg + (size_t)d * HH + f4 * 4;
    atomicAdd(base + 0, v.x);
    atomicAdd(base + 1, v.y);
    atomicAdd(base + 2, v.z);
    atomicAdd(base + 3, v.w);
}

// ---------------- dual GEMM: h = (agg*invdeg) @ Wl^T + x @ Wr^T + bl ----------------
// block: 256 threads -> 16 rows x 128 cols tile. thread: j = tid&127, rowgroup = tid>>7 (8 rows).
// A tiles staged in LDS (natural layout, pad to 132 floats); wave-uniform A reads = broadcast.
__global__ __launch_bounds__(256) void gemm_kernel(
    const float* __restrict__ agg, const float* __restrict__ invdeg,
    const float* __restrict__ x,
    const float* __restrict__ Wl, const float* __restrict__ Wr,
    const float* __restrict__ bl,
    float* __restrict__ h, int N)
{
    __shared__ float a_s[16][132];
    __shared__ float x_s[16][132];
    const int row0 = blockIdx.x * 16;
    const int tid = threadIdx.x;

    // stage 16 rows of agg (scaled) and x: 512 float4 per array
    for (int t = tid; t < 16 * 32; t += 256) {
        int r = t >> 5, c4 = t & 31;
        int row = row0 + r;
        float4 va = make_float4(0.f, 0.f, 0.f, 0.f);
        float4 vx = va;
        if (row < N) {
            va = ((const float4*)(agg + (size_t)row * HH))[c4];
            float id = invdeg[row];
            va.x *= id; va.y *= id; va.z *= id; va.w *= id;
            vx = ((const float4*)(x + (size_t)row * HH))[c4];
        }
        *(float4*)&a_s[r][c4 * 4] = va;
        *(float4*)&x_s[r][c4 * 4] = vx;
    }
    __syncthreads();

    const int j = tid & 127;
    const int rg = tid >> 7;      // 0..1
    float acc[8];
#pragma unroll
    for (int i = 0; i < 8; ++i) acc[i] = 0.f;

    const float4* wlrow = (const float4*)(Wl + j * HH);
    const float4* wrrow = (const float4*)(Wr + j * HH);

    for (int k4 = 0; k4 < 32; ++k4) {
        float4 wl4 = wlrow[k4];
        float4 wr4 = wrrow[k4];
#pragma unroll
        for (int i = 0; i < 8; ++i) {
            int r = rg * 8 + i;
            float4 a4 = *(const float4*)&a_s[r][k4 * 4];
            float4 v4 = *(const float4*)&x_s[r][k4 * 4];
            acc[i] = fmaf(a4.x, wl4.x, acc[i]);
            acc[i] = fmaf(a4.y, wl4.y, acc[i]);
            acc[i] = fmaf(a4.z, wl4.z, acc[i]);
            acc[i] = fmaf(a4.w, wl4.w, acc[i]);
            acc[i] = fmaf(v4.x, wr4.x, acc[i]);
            acc[i] = fmaf(v4.y, wr4.y, acc[i]);
            acc[i] = fmaf(v4.z, wr4.z, acc[i]);
            acc[i] = fmaf(v4.w, wr4.w, acc[i]);
        }
    }

    float bias = bl[j];
#pragma unroll
    for (int i = 0; i < 8; ++i) {
        int row = row0 + rg * 8 + i;
        if (row < N) h[(size_t)row * HH + j] = acc[i] + bias;
    }
}

// ---------------- BN stats: column sums / sumsq ----------------
__global__ void stats_kernel(const float* __restrict__ h, float* __restrict__ stats, int N) {
    int f = threadIdx.x & 127;
    int rg = threadIdx.x >> 7;   // 0..1
    float s = 0.f, s2 = 0.f;
    for (int r = blockIdx.x * 2 + rg; r < N; r += gridDim.x * 2) {
        float v = h[(size_t)r * HH + f];
        s += v;
        s2 += v * v;
    }
    atomicAdd(&stats[f], s);
    atomicAdd(&stats[128 + f], s2);
}

__global__ void bn_finalize_kernel(const float* __restrict__ stats,
                                   const float* __restrict__ gamma,
                                   const float* __restrict__ beta,
                                   float* __restrict__ ab, float invN) {
    int f = threadIdx.x;  // 128 threads
    float mean = stats[f] * invN;
    float var = stats[128 + f] * invN - mean * mean;
    float istd = rsqrtf(var + EPS);
    float a = gamma[f] * istd;
    ab[f] = a;
    ab[128 + f] = beta[f] - mean * a;
}

// ---------------- normalize + relu + residual ----------------
__global__ void bn_relu_res_kernel(const float* __restrict__ h, const float* __restrict__ xin,
                                   const float* __restrict__ ab, float* __restrict__ xout,
                                   int N, int residual) {
    int idx = blockIdx.x * 256 + threadIdx.x;  // one float4 each
    if (idx >= N * 32) return;
    int f4 = idx & 31;
    float4 h4 = ((const float4*)h)[idx];
    float4 a4 = ((const float4*)ab)[f4];
    float4 b4 = ((const float4*)(ab + 128))[f4];
    float4 o;
    o.x = fmaxf(fmaf(h4.x, a4.x, b4.x), 0.f);
    o.y = fmaxf(fmaf(h4.y, a4.y, b4.y), 0.f);
    o.z = fmaxf(fmaf(h4.z, a4.z, b4.z), 0.f);
    o.w = fmaxf(fmaf(h4.w, a4.w, b4.w), 0.f);
    if (residual) {
        float4 xi = ((const float4*)xin)[idx];
        o.x += xi.x; o.y += xi.y; o.z += xi.z; o.w += xi.w;
    }
    ((float4*)xout)[idx] = o;
}

extern "C" void kernel_launch(void* const* d_in, const int* in_sizes, int n_in,
                              void* d_out, int out_size, void* d_ws, size_t ws_size,
                              hipStream_t stream) {
    const float* x     = (const float*)d_in[0];
    const int*   ei    = (const int*)d_in[1];
    const float* Wl    = (const float*)d_in[2];
    const float* bl    = (const float*)d_in[3];
    const float* Wr    = (const float*)d_in[4];
    const float* gamma = (const float*)d_in[5];
    const float* beta  = (const float*)d_in[6];
    float* out = (float*)d_out;

    const int N = in_sizes[0] / HH;
    const int E = in_sizes[1] / 2;
    const int* src = ei;
    const int* dst = ei + E;

    float* ws   = (float*)d_ws;
    float* agg  = ws;                       // N*HH floats (also used as h)
    float* cur  = agg + (size_t)N * HH;     // N*HH floats (ping buffer for x)
    float* deg  = cur + (size_t)N * HH;     // N floats (becomes inv_deg)
    float* stats = deg + N;                 // 256 floats
    float* ab    = stats + 256;             // 256 floats

    // degree -> inv_deg (once)
    hipMemsetAsync(deg, 0, (size_t)N * sizeof(float), stream);
    deg_kernel<<<(E + 255) / 256, 256, 0, stream>>>(dst, deg, E);
    invdeg_kernel<<<(N + 255) / 256, 256, 0, stream>>>(deg, N);

    const int gemm_blocks = (N + 15) / 16;
    const int elem_blocks = (N * 32 + 255) / 256;

    for (int layer = 0; layer < 3; ++layer) {
        const float* xin = (layer == 0) ? x : cur;
        float* xout = (layer == 2) ? out : cur;

        hipMemsetAsync(agg, 0, (size_t)N * HH * sizeof(float), stream);
        hipMemsetAsync(stats, 0, 256 * sizeof(float), stream);

        scatter_kernel<<<(E * 32 + 255) / 256, 256, 0, stream>>>(xin, src, dst, agg, E);

        gemm_kernel<<<gemm_blocks, 256, 0, stream>>>(
            agg, deg, xin,
            Wl + (size_t)layer * HH * HH, Wr + (size_t)layer * HH * HH,
            bl + (size_t)layer * HH,
            agg /* h aliases agg: rows staged to LDS before overwrite */, N);

        stats_kernel<<<256, 256, 0, stream>>>(agg, stats, N);
        bn_finalize_kernel<<<1, 128, 0, stream>>>(
            stats, gamma + (size_t)layer * HH, beta + (size_t)layer * HH, ab, 1.0f / (float)N);

        bn_relu_res_kernel<<<elem_blocks, 256, 0, stream>>>(
            agg, xin, ab, xout, N, layer > 0 ? 1 : 0);
    }
}

// Round 2
// 863.738 us; speedup vs baseline: 5.4499x; 5.4499x over previous
//
#include <hip/hip_runtime.h>

#define HH 128
#define EPS 1e-5f

// ---------------- CSR build (once): histogram, scan, setup, fill ----------------
__global__ void hist_kernel(const int* __restrict__ dst, int* __restrict__ cnt, int E) {
    int e = blockIdx.x * 256 + threadIdx.x;
    if (e < E) atomicAdd(&cnt[dst[e]], 1);
}

// single-block exclusive scan: cnt[N] -> row_ptr[N+1]
__global__ __launch_bounds__(1024) void scan_kernel(const int* __restrict__ cnt,
                                                    int* __restrict__ row_ptr, int N) {
    __shared__ int sums[1024];
    const int t = threadIdx.x;
    const int C = (N + 1023) / 1024;
    const int b = t * C;
    const int e = min(b + C, N);
    int s = 0;
    for (int i = b; i < e; ++i) s += cnt[i];
    sums[t] = s;
    __syncthreads();
    for (int off = 1; off < 1024; off <<= 1) {
        int v = 0;
        if (t >= off) v = sums[t - off];
        __syncthreads();
        if (t >= off) sums[t] += v;
        __syncthreads();
    }
    int run = (t == 0) ? 0 : sums[t - 1];
    for (int i = b; i < e; ++i) { row_ptr[i] = run; run += cnt[i]; }
    if (t == 1023) row_ptr[N] = run;   // == E
}

__global__ void setup_kernel(const int* __restrict__ cnt, const int* __restrict__ row_ptr,
                             float* __restrict__ invdeg, int* __restrict__ pos, int N) {
    int n = blockIdx.x * 256 + threadIdx.x;
    if (n < N) {
        invdeg[n] = 1.0f / fmaxf((float)cnt[n], 1.0f);
        pos[n] = row_ptr[n];
    }
}

__global__ void fill_kernel(const int* __restrict__ src, const int* __restrict__ dst,
                            int* __restrict__ pos, int* __restrict__ edge_csr, int E) {
    int e = blockIdx.x * 256 + threadIdx.x;
    if (e < E) {
        int p = atomicAdd(&pos[dst[e]], 1);
        edge_csr[p] = src[e];
    }
}

// ---------------- gather-aggregate: agg[i] = invdeg[i] * sum_{e in N(i)} x[src_e] ----------------
// 32 threads per node (one float4 lane each), 8 nodes per 256-thread block.
__global__ __launch_bounds__(256) void gather_kernel(
    const float* __restrict__ x, const int* __restrict__ row_ptr,
    const int* __restrict__ edge_csr, const float* __restrict__ invdeg,
    float* __restrict__ agg, int N)
{
    const int node = blockIdx.x * 8 + (threadIdx.x >> 5);
    if (node >= N) return;
    const int f4 = threadIdx.x & 31;
    const int beg = row_ptr[node];
    const int end = row_ptr[node + 1];
    float4 acc = make_float4(0.f, 0.f, 0.f, 0.f);
    int k = beg;
    for (; k + 1 < end; k += 2) {
        int s0 = edge_csr[k];
        int s1 = edge_csr[k + 1];
        float4 v0 = ((const float4*)(x + (size_t)s0 * HH))[f4];
        float4 v1 = ((const float4*)(x + (size_t)s1 * HH))[f4];
        acc.x += v0.x + v1.x;
        acc.y += v0.y + v1.y;
        acc.z += v0.z + v1.z;
        acc.w += v0.w + v1.w;
    }
    if (k < end) {
        int s0 = edge_csr[k];
        float4 v0 = ((const float4*)(x + (size_t)s0 * HH))[f4];
        acc.x += v0.x; acc.y += v0.y; acc.z += v0.z; acc.w += v0.w;
    }
    const float id = invdeg[node];
    acc.x *= id; acc.y *= id; acc.z *= id; acc.w *= id;
    ((float4*)(agg + (size_t)node * HH))[f4] = acc;
}

// ---------------- dual GEMM: h = agg @ Wl^T + x @ Wr^T + bl (invdeg pre-applied) ----------------
__global__ __launch_bounds__(256) void gemm_kernel(
    const float* __restrict__ agg, const float* __restrict__ x,
    const float* __restrict__ Wl, const float* __restrict__ Wr,
    const float* __restrict__ bl,
    float* __restrict__ h, int N)
{
    __shared__ float a_s[16][132];
    __shared__ float x_s[16][132];
    const int row0 = blockIdx.x * 16;
    const int tid = threadIdx.x;

    for (int t = tid; t < 16 * 32; t += 256) {
        int r = t >> 5, c4 = t & 31;
        int row = row0 + r;
        float4 va = make_float4(0.f, 0.f, 0.f, 0.f);
        float4 vx = va;
        if (row < N) {
            va = ((const float4*)(agg + (size_t)row * HH))[c4];
            vx = ((const float4*)(x + (size_t)row * HH))[c4];
        }
        *(float4*)&a_s[r][c4 * 4] = va;
        *(float4*)&x_s[r][c4 * 4] = vx;
    }
    __syncthreads();

    const int j = tid & 127;
    const int rg = tid >> 7;
    float acc[8];
#pragma unroll
    for (int i = 0; i < 8; ++i) acc[i] = 0.f;

    const float4* wlrow = (const float4*)(Wl + j * HH);
    const float4* wrrow = (const float4*)(Wr + j * HH);

    for (int k4 = 0; k4 < 32; ++k4) {
        float4 wl4 = wlrow[k4];
        float4 wr4 = wrrow[k4];
#pragma unroll
        for (int i = 0; i < 8; ++i) {
            int r = rg * 8 + i;
            float4 a4 = *(const float4*)&a_s[r][k4 * 4];
            float4 v4 = *(const float4*)&x_s[r][k4 * 4];
            acc[i] = fmaf(a4.x, wl4.x, acc[i]);
            acc[i] = fmaf(a4.y, wl4.y, acc[i]);
            acc[i] = fmaf(a4.z, wl4.z, acc[i]);
            acc[i] = fmaf(a4.w, wl4.w, acc[i]);
            acc[i] = fmaf(v4.x, wr4.x, acc[i]);
            acc[i] = fmaf(v4.y, wr4.y, acc[i]);
            acc[i] = fmaf(v4.z, wr4.z, acc[i]);
            acc[i] = fmaf(v4.w, wr4.w, acc[i]);
        }
    }

    float bias = bl[j];
#pragma unroll
    for (int i = 0; i < 8; ++i) {
        int row = row0 + rg * 8 + i;
        if (row < N) h[(size_t)row * HH + j] = acc[i] + bias;
    }
}

// ---------------- BN stats ----------------
__global__ void stats_kernel(const float* __restrict__ h, float* __restrict__ stats, int N) {
    int f = threadIdx.x & 127;
    int rg = threadIdx.x >> 7;
    float s = 0.f, s2 = 0.f;
    for (int r = blockIdx.x * 2 + rg; r < N; r += gridDim.x * 2) {
        float v = h[(size_t)r * HH + f];
        s += v;
        s2 += v * v;
    }
    atomicAdd(&stats[f], s);
    atomicAdd(&stats[128 + f], s2);
}

__global__ void bn_finalize_kernel(const float* __restrict__ stats,
                                   const float* __restrict__ gamma,
                                   const float* __restrict__ beta,
                                   float* __restrict__ ab, float invN) {
    int f = threadIdx.x;
    float mean = stats[f] * invN;
    float var = stats[128 + f] * invN - mean * mean;
    float istd = rsqrtf(var + EPS);
    float a = gamma[f] * istd;
    ab[f] = a;
    ab[128 + f] = beta[f] - mean * a;
}

// ---------------- normalize + relu + residual ----------------
__global__ void bn_relu_res_kernel(const float* __restrict__ h, const float* __restrict__ xin,
                                   const float* __restrict__ ab, float* __restrict__ xout,
                                   int N, int residual) {
    int idx = blockIdx.x * 256 + threadIdx.x;
    if (idx >= N * 32) return;
    int f4 = idx & 31;
    float4 h4 = ((const float4*)h)[idx];
    float4 a4 = ((const float4*)ab)[f4];
    float4 b4 = ((const float4*)(ab + 128))[f4];
    float4 o;
    o.x = fmaxf(fmaf(h4.x, a4.x, b4.x), 0.f);
    o.y = fmaxf(fmaf(h4.y, a4.y, b4.y), 0.f);
    o.z = fmaxf(fmaf(h4.z, a4.z, b4.z), 0.f);
    o.w = fmaxf(fmaf(h4.w, a4.w, b4.w), 0.f);
    if (residual) {
        float4 xi = ((const float4*)xin)[idx];
        o.x += xi.x; o.y += xi.y; o.z += xi.z; o.w += xi.w;
    }
    ((float4*)xout)[idx] = o;
}

extern "C" void kernel_launch(void* const* d_in, const int* in_sizes, int n_in,
                              void* d_out, int out_size, void* d_ws, size_t ws_size,
                              hipStream_t stream) {
    const float* x     = (const float*)d_in[0];
    const int*   ei    = (const int*)d_in[1];
    const float* Wl    = (const float*)d_in[2];
    const float* bl    = (const float*)d_in[3];
    const float* Wr    = (const float*)d_in[4];
    const float* gamma = (const float*)d_in[5];
    const float* beta  = (const float*)d_in[6];
    float* out = (float*)d_out;

    const int N = in_sizes[0] / HH;
    const int E = in_sizes[1] / 2;
    const int* src = ei;
    const int* dst = ei + E;

    float* ws    = (float*)d_ws;
    float* agg   = ws;                        // N*HH floats (aliased as h)
    float* cur   = agg + (size_t)N * HH;      // N*HH floats
    float* invdeg = cur + (size_t)N * HH;     // N floats
    float* stats = invdeg + N;                // 256 floats
    float* ab    = stats + 256;               // 256 floats
    int* cnt     = (int*)(ab + 256);          // N ints
    int* row_ptr = cnt + N;                   // N+1 ints
    int* pos     = row_ptr + N + 1;           // N ints
    int* edge_csr = pos + N;                  // E ints

    // ---- CSR build (once) ----
    hipMemsetAsync(cnt, 0, (size_t)N * sizeof(int), stream);
    hist_kernel<<<(E + 255) / 256, 256, 0, stream>>>(dst, cnt, E);
    scan_kernel<<<1, 1024, 0, stream>>>(cnt, row_ptr, N);
    setup_kernel<<<(N + 255) / 256, 256, 0, stream>>>(cnt, row_ptr, invdeg, pos, N);
    fill_kernel<<<(E + 255) / 256, 256, 0, stream>>>(src, dst, pos, edge_csr, E);

    const int gather_blocks = (N + 7) / 8;
    const int gemm_blocks = (N + 15) / 16;
    const int elem_blocks = (N * 32 + 255) / 256;

    for (int layer = 0; layer < 3; ++layer) {
        const float* xin = (layer == 0) ? x : cur;
        float* xout = (layer == 2) ? out : cur;

        hipMemsetAsync(stats, 0, 256 * sizeof(float), stream);

        gather_kernel<<<gather_blocks, 256, 0, stream>>>(
            xin, row_ptr, edge_csr, invdeg, agg, N);

        gemm_kernel<<<gemm_blocks, 256, 0, stream>>>(
            agg, xin,
            Wl + (size_t)layer * HH * HH, Wr + (size_t)layer * HH * HH,
            bl + (size_t)layer * HH,
            agg /* h aliases agg: rows staged to LDS before overwrite */, N);

        stats_kernel<<<256, 256, 0, stream>>>(agg, stats, N);
        bn_finalize_kernel<<<1, 128, 0, stream>>>(
            stats, gamma + (size_t)layer * HH, beta + (size_t)layer * HH, ab, 1.0f / (float)N);

        bn_relu_res_kernel<<<elem_blocks, 256, 0, stream>>>(
            agg, xin, ab, xout, N, layer > 0 ? 1 : 0);
    }
}

// Round 3
// 437.871 us; speedup vs baseline: 10.7503x; 1.9726x over previous
//
#include <hip/hip_runtime.h>

#define HH 128
#define EPS 1e-5f

typedef __bf16 bf16x8 __attribute__((ext_vector_type(8)));
typedef float f32x4 __attribute__((ext_vector_type(4)));

__device__ __forceinline__ unsigned f2bf(float f) {
    unsigned u = __builtin_bit_cast(unsigned, f);
    return (u + 0x7FFFu + ((u >> 16) & 1u)) >> 16;   // RNE
}
__device__ __forceinline__ float bflo(unsigned w) { return __builtin_bit_cast(float, w << 16); }
__device__ __forceinline__ float bfhi(unsigned w) { return __builtin_bit_cast(float, w & 0xFFFF0000u); }

// ---------------- CSR build (once) ----------------
__global__ void hist_kernel(const int* __restrict__ dst, int* __restrict__ cnt, int E) {
    int e = blockIdx.x * 256 + threadIdx.x;
    if (e < E) atomicAdd(&cnt[dst[e]], 1);
}

__global__ __launch_bounds__(1024) void scan_kernel(const int* __restrict__ cnt,
                                                    int* __restrict__ row_ptr, int N) {
    __shared__ int sums[1024];
    const int t = threadIdx.x;
    const int C = (N + 1023) / 1024;
    const int b = t * C;
    const int e = min(b + C, N);
    int s = 0;
    for (int i = b; i < e; ++i) s += cnt[i];
    sums[t] = s;
    __syncthreads();
    for (int off = 1; off < 1024; off <<= 1) {
        int v = 0;
        if (t >= off) v = sums[t - off];
        __syncthreads();
        if (t >= off) sums[t] += v;
        __syncthreads();
    }
    int run = (t == 0) ? 0 : sums[t - 1];
    for (int i = b; i < e; ++i) { row_ptr[i] = run; run += cnt[i]; }
    if (t == 1023) row_ptr[N] = run;
}

__global__ void setup_kernel(const int* __restrict__ cnt, const int* __restrict__ row_ptr,
                             float* __restrict__ invdeg, int* __restrict__ pos, int N) {
    int n = blockIdx.x * 256 + threadIdx.x;
    if (n < N) {
        invdeg[n] = 1.0f / fmaxf((float)cnt[n], 1.0f);
        pos[n] = row_ptr[n];
    }
}

__global__ void fill_kernel(const int* __restrict__ src, const int* __restrict__ dst,
                            int* __restrict__ pos, int* __restrict__ edge_csr, int E) {
    int e = blockIdx.x * 256 + threadIdx.x;
    if (e < E) {
        int p = atomicAdd(&pos[dst[e]], 1);
        edge_csr[p] = src[e];
    }
}

// ---------------- converts ----------------
__global__ void convert_x_kernel(const float* __restrict__ x, ushort* __restrict__ xb, int n4) {
    int idx = blockIdx.x * 256 + threadIdx.x;   // float4 units
    if (idx >= n4) return;
    float4 v = ((const float4*)x)[idx];
    uint2 o;
    o.x = f2bf(v.x) | (f2bf(v.y) << 16);
    o.y = f2bf(v.z) | (f2bf(v.w) << 16);
    ((uint2*)xb)[idx] = o;
}

// Wb[layer][col][k2], k2<128 -> Wl[col][k2], else Wr[col][k2-128]
__global__ void convert_w_kernel(const float* __restrict__ Wl, const float* __restrict__ Wr,
                                 ushort* __restrict__ Wb, int total) {
    int idx = blockIdx.x * 256 + threadIdx.x;
    if (idx >= total) return;
    int l = idx / (HH * 256);
    int rem = idx - l * (HH * 256);
    int col = rem >> 8;
    int k = rem & 255;
    float v = (k < HH) ? Wl[(size_t)l * HH * HH + col * HH + k]
                       : Wr[(size_t)l * HH * HH + col * HH + (k - HH)];
    Wb[idx] = (ushort)f2bf(v);
}

__global__ void zero_pad_kernel(ushort* __restrict__ aggb, ushort* __restrict__ xb,
                                int N, int MP) {
    int i = blockIdx.x * 256 + threadIdx.x;     // ushort index into pad region
    int total = (MP - N) * HH;
    if (i < total) {
        aggb[(size_t)N * HH + i] = 0;
        xb[(size_t)N * HH + i] = 0;
    }
}

// ---------------- gather (bf16 in, f32 accum, bf16 out) ----------------
// 16 threads per node, 8 features each.
__global__ __launch_bounds__(256) void gather_kernel(
    const ushort* __restrict__ xb, const int* __restrict__ row_ptr,
    const int* __restrict__ edge_csr, const float* __restrict__ invdeg,
    ushort* __restrict__ aggb, int N)
{
    const int node = blockIdx.x * 16 + (threadIdx.x >> 4);
    if (node >= N) return;
    const int l16 = threadIdx.x & 15;
    const int beg = row_ptr[node], end = row_ptr[node + 1];
    float a0=0,a1=0,a2=0,a3=0,a4=0,a5=0,a6=0,a7=0;
    int e = beg;
    for (; e + 1 < end; e += 2) {
        int s0 = edge_csr[e], s1 = edge_csr[e + 1];
        uint4 v0 = *(const uint4*)(xb + (size_t)s0 * HH + l16 * 8);
        uint4 v1 = *(const uint4*)(xb + (size_t)s1 * HH + l16 * 8);
        a0 += bflo(v0.x) + bflo(v1.x);  a1 += bfhi(v0.x) + bfhi(v1.x);
        a2 += bflo(v0.y) + bflo(v1.y);  a3 += bfhi(v0.y) + bfhi(v1.y);
        a4 += bflo(v0.z) + bflo(v1.z);  a5 += bfhi(v0.z) + bfhi(v1.z);
        a6 += bflo(v0.w) + bflo(v1.w);  a7 += bfhi(v0.w) + bfhi(v1.w);
    }
    if (e < end) {
        int s0 = edge_csr[e];
        uint4 v0 = *(const uint4*)(xb + (size_t)s0 * HH + l16 * 8);
        a0 += bflo(v0.x); a1 += bfhi(v0.x);
        a2 += bflo(v0.y); a3 += bfhi(v0.y);
        a4 += bflo(v0.z); a5 += bfhi(v0.z);
        a6 += bflo(v0.w); a7 += bfhi(v0.w);
    }
    const float id = invdeg[node];
    uint4 o;
    o.x = f2bf(a0 * id) | (f2bf(a1 * id) << 16);
    o.y = f2bf(a2 * id) | (f2bf(a3 * id) << 16);
    o.z = f2bf(a4 * id) | (f2bf(a5 * id) << 16);
    o.w = f2bf(a6 * id) | (f2bf(a7 * id) << 16);
    *(uint4*)(aggb + (size_t)node * HH + l16 * 8) = o;
}

// ---------------- MFMA GEMM: h = [agg|x] @ [Wl|Wr]^T + bl, fused BN stats ----------------
// block = 256 thr = 4 waves; block tile 64 rows x 128 cols; wave tile 64 rows x 32 cols.
// B-frags (2 col-tiles x 8 k-steps) held in VGPRs; A-frags streamed from global. No LDS in k-loop.
__global__ __launch_bounds__(256) void mfma_gemm_kernel(
    const ushort* __restrict__ aggb, const ushort* __restrict__ xb,
    const ushort* __restrict__ Wb, const float* __restrict__ bl,
    ushort* __restrict__ hb, float* __restrict__ stats, int N)
{
    const int tid = threadIdx.x;
    const int lane = tid & 63;
    const int wave = tid >> 6;
    const int m0 = blockIdx.x * 64;
    const int l15 = lane & 15;
    const int lg = lane >> 4;
    const int colbase = wave * 32;

    bf16x8 bfr[8][2];
#pragma unroll
    for (int s = 0; s < 8; ++s)
#pragma unroll
        for (int ct = 0; ct < 2; ++ct) {
            int col = colbase + ct * 16 + l15;
            bfr[s][ct] = *(const bf16x8*)(Wb + (size_t)col * 256 + s * 32 + lg * 8);
        }

    f32x4 acc[4][2];
#pragma unroll
    for (int rt = 0; rt < 4; ++rt)
#pragma unroll
        for (int ct = 0; ct < 2; ++ct)
            acc[rt][ct] = (f32x4){0.f, 0.f, 0.f, 0.f};

#pragma unroll
    for (int s = 0; s < 8; ++s) {
        const ushort* Abase = (s < 4) ? aggb : xb;
        const int ks = (s & 3) * 32;
#pragma unroll
        for (int rt = 0; rt < 4; ++rt) {
            int row = m0 + rt * 16 + l15;
            bf16x8 a = *(const bf16x8*)(Abase + (size_t)row * HH + ks + lg * 8);
#pragma unroll
            for (int ct = 0; ct < 2; ++ct)
                acc[rt][ct] = __builtin_amdgcn_mfma_f32_16x16x32_bf16(a, bfr[s][ct], acc[rt][ct], 0, 0, 0);
        }
    }

    __shared__ float s_sum[128];
    __shared__ float s_sum2[128];
    if (tid < 128) { s_sum[tid] = 0.f; s_sum2[tid] = 0.f; }
    __syncthreads();

#pragma unroll
    for (int ct = 0; ct < 2; ++ct) {
        const int col = colbase + ct * 16 + l15;
        const float bias = bl[col];
        float s1 = 0.f, s2 = 0.f;
#pragma unroll
        for (int rt = 0; rt < 4; ++rt) {
#pragma unroll
            for (int r = 0; r < 4; ++r) {
                int row = m0 + rt * 16 + lg * 4 + r;
                float v = acc[rt][ct][r] + bias;
                if (row < N) {
                    hb[(size_t)row * HH + col] = (ushort)f2bf(v);
                    s1 += v;
                    s2 += v * v;
                }
            }
        }
        atomicAdd(&s_sum[col], s1);
        atomicAdd(&s_sum2[col], s2);
    }
    __syncthreads();
    if (tid < 128) {
        atomicAdd(&stats[tid], s_sum[tid]);
        atomicAdd(&stats[128 + tid], s_sum2[tid]);
    }
}

// ---------------- BN finalize ----------------
__global__ void bn_finalize_kernel(const float* __restrict__ stats,
                                   const float* __restrict__ gamma,
                                   const float* __restrict__ beta,
                                   float* __restrict__ ab, float invN) {
    int f = threadIdx.x;
    float mean = stats[f] * invN;
    float var = stats[128 + f] * invN - mean * mean;
    float istd = rsqrtf(var + EPS);
    float a = gamma[f] * istd;
    ab[f] = a;
    ab[128 + f] = beta[f] - mean * a;
}

// ---------------- normalize + relu + residual (+ bf16 copy for next layer) ----------------
__global__ void bn_relu_res_kernel(const ushort* __restrict__ hb, const float* __restrict__ xin,
                                   const float* __restrict__ ab, float* __restrict__ xout,
                                   ushort* __restrict__ xbout, int n4, int residual, int write_bf) {
    int idx = blockIdx.x * 256 + threadIdx.x;   // float4 units over N*32
    if (idx >= n4) return;
    int f4 = idx & 31;
    uint2 hw = ((const uint2*)hb)[idx];
    float4 h4 = make_float4(bflo(hw.x), bfhi(hw.x), bflo(hw.y), bfhi(hw.y));
    float4 a4 = ((const float4*)ab)[f4];
    float4 b4 = ((const float4*)(ab + 128))[f4];
    float4 o;
    o.x = fmaxf(fmaf(h4.x, a4.x, b4.x), 0.f);
    o.y = fmaxf(fmaf(h4.y, a4.y, b4.y), 0.f);
    o.z = fmaxf(fmaf(h4.z, a4.z, b4.z), 0.f);
    o.w = fmaxf(fmaf(h4.w, a4.w, b4.w), 0.f);
    if (residual) {
        float4 xi = ((const float4*)xin)[idx];
        o.x += xi.x; o.y += xi.y; o.z += xi.z; o.w += xi.w;
    }
    ((float4*)xout)[idx] = o;
    if (write_bf) {
        uint2 ob;
        ob.x = f2bf(o.x) | (f2bf(o.y) << 16);
        ob.y = f2bf(o.z) | (f2bf(o.w) << 16);
        ((uint2*)xbout)[idx] = ob;
    }
}

extern "C" void kernel_launch(void* const* d_in, const int* in_sizes, int n_in,
                              void* d_out, int out_size, void* d_ws, size_t ws_size,
                              hipStream_t stream) {
    const float* x     = (const float*)d_in[0];
    const int*   ei    = (const int*)d_in[1];
    const float* Wl    = (const float*)d_in[2];
    const float* bl    = (const float*)d_in[3];
    const float* Wr    = (const float*)d_in[4];
    const float* gamma = (const float*)d_in[5];
    const float* beta  = (const float*)d_in[6];
    float* out = (float*)d_out;

    const int N = in_sizes[0] / HH;
    const int E = in_sizes[1] / 2;
    const int MP = ((N + 63) / 64) * 64;
    const int* src = ei;
    const int* dst = ei + E;

    char* p = (char*)d_ws;
    float* cur      = (float*)p;  p += (size_t)MP * HH * 4;
    ushort* aggb    = (ushort*)p; p += (size_t)MP * HH * 2;   // h aliases this (bf16)
    ushort* xb      = (ushort*)p; p += (size_t)MP * HH * 2;
    ushort* Wb      = (ushort*)p; p += (size_t)3 * HH * 256 * 2;
    float* invdeg   = (float*)p;  p += (size_t)N * 4;
    float* stats    = (float*)p;  p += 256 * 4;
    float* ab       = (float*)p;  p += 256 * 4;
    int* cnt        = (int*)p;    p += (size_t)N * 4;
    int* row_ptr    = (int*)p;    p += (size_t)(N + 4) * 4;
    int* pos        = (int*)p;    p += (size_t)N * 4;
    int* edge_csr   = (int*)p;    p += (size_t)E * 4;

    // ---- CSR build (once) ----
    hipMemsetAsync(cnt, 0, (size_t)N * sizeof(int), stream);
    hist_kernel<<<(E + 255) / 256, 256, 0, stream>>>(dst, cnt, E);
    scan_kernel<<<1, 1024, 0, stream>>>(cnt, row_ptr, N);
    setup_kernel<<<(N + 255) / 256, 256, 0, stream>>>(cnt, row_ptr, invdeg, pos, N);
    fill_kernel<<<(E + 255) / 256, 256, 0, stream>>>(src, dst, pos, edge_csr, E);

    // ---- converts / pad zero (once) ----
    int padElems = (MP - N) * HH;
    if (padElems > 0)
        zero_pad_kernel<<<(padElems + 255) / 256, 256, 0, stream>>>(aggb, xb, N, MP);
    const int wtotal = 3 * HH * 256;
    convert_w_kernel<<<(wtotal + 255) / 256, 256, 0, stream>>>(Wl, Wr, Wb, wtotal);
    const int n4 = N * (HH / 4);
    convert_x_kernel<<<(n4 + 255) / 256, 256, 0, stream>>>(x, xb, n4);

    const int gather_blocks = (N + 15) / 16;
    const int gemm_blocks = MP / 64;
    const int elem_blocks = (n4 + 255) / 256;

    for (int layer = 0; layer < 3; ++layer) {
        hipMemsetAsync(stats, 0, 256 * sizeof(float), stream);

        gather_kernel<<<gather_blocks, 256, 0, stream>>>(
            xb, row_ptr, edge_csr, invdeg, aggb, N);

        mfma_gemm_kernel<<<gemm_blocks, 256, 0, stream>>>(
            aggb, xb, Wb + (size_t)layer * HH * 256,
            bl + (size_t)layer * HH,
            aggb /* hb aliases aggb */, stats, N);

        bn_finalize_kernel<<<1, 128, 0, stream>>>(
            stats, gamma + (size_t)layer * HH, beta + (size_t)layer * HH, ab, 1.0f / (float)N);

        bn_relu_res_kernel<<<elem_blocks, 256, 0, stream>>>(
            aggb /* hb */, cur, ab,
            (layer == 2) ? out : cur, xb,
            n4, layer > 0 ? 1 : 0, layer < 2 ? 1 : 0);
    }
}

// Round 4
// 370.248 us; speedup vs baseline: 12.7138x; 1.1826x over previous
//
#include <hip/hip_runtime.h>

#define HH 128
#define EPS 1e-5f

typedef __bf16 bf16x8 __attribute__((ext_vector_type(8)));
typedef float f32x4 __attribute__((ext_vector_type(4)));

__device__ __forceinline__ unsigned f2bf(float f) {
    unsigned u = __builtin_bit_cast(unsigned, f);
    return (u + 0x7FFFu + ((u >> 16) & 1u)) >> 16;   // RNE
}
__device__ __forceinline__ float bflo(unsigned w) { return __builtin_bit_cast(float, w << 16); }
__device__ __forceinline__ float bfhi(unsigned w) { return __builtin_bit_cast(float, w & 0xFFFF0000u); }

// ---------------- CSR build (once) ----------------
__global__ void hist_kernel(const int* __restrict__ dst, int* __restrict__ cnt, int E) {
    int e = blockIdx.x * 256 + threadIdx.x;
    if (e < E) atomicAdd(&cnt[dst[e]], 1);
}

// phase 1: per-block partial sums over chunk = ceil(N/256)
__global__ __launch_bounds__(256) void scan_partial_kernel(const int* __restrict__ cnt,
                                                           int* __restrict__ bsum, int N) {
    __shared__ int red[256];
    const int chunk = (N + 255) / 256;
    const int b = blockIdx.x, t = threadIdx.x;
    const int beg = b * chunk;
    const int end = min(beg + chunk, N);
    int s = 0;
    for (int i = beg + t; i < end; i += 256) s += cnt[i];
    red[t] = s;
    __syncthreads();
    for (int off = 128; off > 0; off >>= 1) {
        if (t < off) red[t] += red[t + off];
        __syncthreads();
    }
    if (t == 0) bsum[b] = red[0];
}

// phase 2: exclusive scan of the 256 block sums (in place)
__global__ __launch_bounds__(256) void scan_bsum_kernel(int* __restrict__ bsum) {
    __shared__ int s[256];
    const int t = threadIdx.x;
    s[t] = bsum[t];
    __syncthreads();
    for (int off = 1; off < 256; off <<= 1) {
        int u = (t >= off) ? s[t - off] : 0;
        __syncthreads();
        s[t] += u;
        __syncthreads();
    }
    bsum[t] = (t == 0) ? 0 : s[t - 1];
}

// phase 3: per-block exclusive scan + write row_ptr/pos/invdeg (fuses old setup_kernel)
__global__ __launch_bounds__(256) void scan_write_kernel(
    const int* __restrict__ cnt, const int* __restrict__ bsum,
    int* __restrict__ row_ptr, float* __restrict__ invdeg,
    int* __restrict__ pos, int N, int E)
{
    __shared__ int s[256];
    const int chunk = (N + 255) / 256;
    const int SUB = (chunk + 255) / 256;
    const int b = blockIdx.x, t = threadIdx.x;
    const int beg = b * chunk;
    const int end = min(beg + chunk, N);
    const int tb = min(beg + t * SUB, end);
    const int te = min(tb + SUB, end);
    int sum = 0;
    for (int i = tb; i < te; ++i) sum += cnt[i];
    s[t] = sum;
    __syncthreads();
    for (int off = 1; off < 256; off <<= 1) {
        int u = (t >= off) ? s[t - off] : 0;
        __syncthreads();
        s[t] += u;
        __syncthreads();
    }
    int run = bsum[b] + ((t == 0) ? 0 : s[t - 1]);
    for (int i = tb; i < te; ++i) {
        row_ptr[i] = run;
        pos[i] = run;
        invdeg[i] = 1.0f / fmaxf((float)cnt[i], 1.0f);
        run += cnt[i];
    }
    if (b == 0 && t == 0) row_ptr[N] = E;
}

__global__ void fill_kernel(const int* __restrict__ src, const int* __restrict__ dst,
                            int* __restrict__ pos, int* __restrict__ edge_csr, int E) {
    int e = blockIdx.x * 256 + threadIdx.x;
    if (e < E) {
        int p = atomicAdd(&pos[dst[e]], 1);
        edge_csr[p] = src[e];
    }
}

// ---------------- converts ----------------
__global__ void convert_x_kernel(const float* __restrict__ x, ushort* __restrict__ xb, int n4) {
    int idx = blockIdx.x * 256 + threadIdx.x;   // float4 units
    if (idx >= n4) return;
    float4 v = ((const float4*)x)[idx];
    uint2 o;
    o.x = f2bf(v.x) | (f2bf(v.y) << 16);
    o.y = f2bf(v.z) | (f2bf(v.w) << 16);
    ((uint2*)xb)[idx] = o;
}

// Wb[layer][col][k2], k2<128 -> Wl[col][k2], else Wr[col][k2-128]
__global__ void convert_w_kernel(const float* __restrict__ Wl, const float* __restrict__ Wr,
                                 ushort* __restrict__ Wb, int total) {
    int idx = blockIdx.x * 256 + threadIdx.x;
    if (idx >= total) return;
    int l = idx / (HH * 256);
    int rem = idx - l * (HH * 256);
    int col = rem >> 8;
    int k = rem & 255;
    float v = (k < HH) ? Wl[(size_t)l * HH * HH + col * HH + k]
                       : Wr[(size_t)l * HH * HH + col * HH + (k - HH)];
    Wb[idx] = (ushort)f2bf(v);
}

__global__ void zero_pad_kernel(ushort* __restrict__ aggb, ushort* __restrict__ xb,
                                int N, int MP) {
    int i = blockIdx.x * 256 + threadIdx.x;
    int total = (MP - N) * HH;
    if (i < total) {
        aggb[(size_t)N * HH + i] = 0;
        xb[(size_t)N * HH + i] = 0;
    }
}

// ---------------- gather (bf16 in, f32 accum, bf16 out) ----------------
__global__ __launch_bounds__(256) void gather_kernel(
    const ushort* __restrict__ xb, const int* __restrict__ row_ptr,
    const int* __restrict__ edge_csr, const float* __restrict__ invdeg,
    ushort* __restrict__ aggb, int N)
{
    const int node = blockIdx.x * 16 + (threadIdx.x >> 4);
    if (node >= N) return;
    const int l16 = threadIdx.x & 15;
    const int beg = row_ptr[node], end = row_ptr[node + 1];
    float a0=0,a1=0,a2=0,a3=0,a4=0,a5=0,a6=0,a7=0;
    int e = beg;
    for (; e + 1 < end; e += 2) {
        int s0 = edge_csr[e], s1 = edge_csr[e + 1];
        uint4 v0 = *(const uint4*)(xb + (size_t)s0 * HH + l16 * 8);
        uint4 v1 = *(const uint4*)(xb + (size_t)s1 * HH + l16 * 8);
        a0 += bflo(v0.x) + bflo(v1.x);  a1 += bfhi(v0.x) + bfhi(v1.x);
        a2 += bflo(v0.y) + bflo(v1.y);  a3 += bfhi(v0.y) + bfhi(v1.y);
        a4 += bflo(v0.z) + bflo(v1.z);  a5 += bfhi(v0.z) + bfhi(v1.z);
        a6 += bflo(v0.w) + bflo(v1.w);  a7 += bfhi(v0.w) + bfhi(v1.w);
    }
    if (e < end) {
        int s0 = edge_csr[e];
        uint4 v0 = *(const uint4*)(xb + (size_t)s0 * HH + l16 * 8);
        a0 += bflo(v0.x); a1 += bfhi(v0.x);
        a2 += bflo(v0.y); a3 += bfhi(v0.y);
        a4 += bflo(v0.z); a5 += bfhi(v0.z);
        a6 += bflo(v0.w); a7 += bfhi(v0.w);
    }
    const float id = invdeg[node];
    uint4 o;
    o.x = f2bf(a0 * id) | (f2bf(a1 * id) << 16);
    o.y = f2bf(a2 * id) | (f2bf(a3 * id) << 16);
    o.z = f2bf(a4 * id) | (f2bf(a5 * id) << 16);
    o.w = f2bf(a6 * id) | (f2bf(a7 * id) << 16);
    *(uint4*)(aggb + (size_t)node * HH + l16 * 8) = o;
}

// ---------------- MFMA GEMM: h = [agg|x] @ [Wl|Wr]^T + bl, fused BN stats ----------------
__global__ __launch_bounds__(256) void mfma_gemm_kernel(
    const ushort* __restrict__ aggb, const ushort* __restrict__ xb,
    const ushort* __restrict__ Wb, const float* __restrict__ bl,
    ushort* __restrict__ hb, float* __restrict__ stats, int N)
{
    const int tid = threadIdx.x;
    const int lane = tid & 63;
    const int wave = tid >> 6;
    const int m0 = blockIdx.x * 64;
    const int l15 = lane & 15;
    const int lg = lane >> 4;
    const int colbase = wave * 32;

    bf16x8 bfr[8][2];
#pragma unroll
    for (int s = 0; s < 8; ++s)
#pragma unroll
        for (int ct = 0; ct < 2; ++ct) {
            int col = colbase + ct * 16 + l15;
            bfr[s][ct] = *(const bf16x8*)(Wb + (size_t)col * 256 + s * 32 + lg * 8);
        }

    f32x4 acc[4][2];
#pragma unroll
    for (int rt = 0; rt < 4; ++rt)
#pragma unroll
        for (int ct = 0; ct < 2; ++ct)
            acc[rt][ct] = (f32x4){0.f, 0.f, 0.f, 0.f};

#pragma unroll
    for (int s = 0; s < 8; ++s) {
        const ushort* Abase = (s < 4) ? aggb : xb;
        const int ks = (s & 3) * 32;
#pragma unroll
        for (int rt = 0; rt < 4; ++rt) {
            int row = m0 + rt * 16 + l15;
            bf16x8 a = *(const bf16x8*)(Abase + (size_t)row * HH + ks + lg * 8);
#pragma unroll
            for (int ct = 0; ct < 2; ++ct)
                acc[rt][ct] = __builtin_amdgcn_mfma_f32_16x16x32_bf16(a, bfr[s][ct], acc[rt][ct], 0, 0, 0);
        }
    }

    __shared__ float s_sum[128];
    __shared__ float s_sum2[128];
    if (tid < 128) { s_sum[tid] = 0.f; s_sum2[tid] = 0.f; }
    __syncthreads();

#pragma unroll
    for (int ct = 0; ct < 2; ++ct) {
        const int col = colbase + ct * 16 + l15;
        const float bias = bl[col];
        float s1 = 0.f, s2 = 0.f;
#pragma unroll
        for (int rt = 0; rt < 4; ++rt) {
#pragma unroll
            for (int r = 0; r < 4; ++r) {
                int row = m0 + rt * 16 + lg * 4 + r;
                float v = acc[rt][ct][r] + bias;
                if (row < N) {
                    hb[(size_t)row * HH + col] = (ushort)f2bf(v);
                    s1 += v;
                    s2 += v * v;
                }
            }
        }
        atomicAdd(&s_sum[col], s1);
        atomicAdd(&s_sum2[col], s2);
    }
    __syncthreads();
    if (tid < 128) {
        atomicAdd(&stats[tid], s_sum[tid]);
        atomicAdd(&stats[128 + tid], s_sum2[tid]);
    }
}

// ---------------- normalize + relu + residual (BN finalize fused in) ----------------
__global__ __launch_bounds__(256) void bn_relu_res_kernel(
    const ushort* __restrict__ hb, const float* __restrict__ xin,
    const float* __restrict__ stats, const float* __restrict__ gamma,
    const float* __restrict__ beta, float invN,
    float* __restrict__ xout, ushort* __restrict__ xbout,
    int n4, int residual, int write_bf)
{
    __shared__ float s_ab[256];
    const int t = threadIdx.x;
    if (t < 128) {
        float mean = stats[t] * invN;
        float var = stats[128 + t] * invN - mean * mean;
        float istd = rsqrtf(var + EPS);
        float a = gamma[t] * istd;
        s_ab[t] = a;
        s_ab[128 + t] = beta[t] - mean * a;
    }
    __syncthreads();
    int idx = blockIdx.x * 256 + t;   // float4 units over N*32
    if (idx >= n4) return;
    int f4 = idx & 31;
    uint2 hw = ((const uint2*)hb)[idx];
    float4 h4 = make_float4(bflo(hw.x), bfhi(hw.x), bflo(hw.y), bfhi(hw.y));
    float4 a4 = *(const float4*)&s_ab[f4 * 4];
    float4 b4 = *(const float4*)&s_ab[128 + f4 * 4];
    float4 o;
    o.x = fmaxf(fmaf(h4.x, a4.x, b4.x), 0.f);
    o.y = fmaxf(fmaf(h4.y, a4.y, b4.y), 0.f);
    o.z = fmaxf(fmaf(h4.z, a4.z, b4.z), 0.f);
    o.w = fmaxf(fmaf(h4.w, a4.w, b4.w), 0.f);
    if (residual) {
        float4 xi = ((const float4*)xin)[idx];
        o.x += xi.x; o.y += xi.y; o.z += xi.z; o.w += xi.w;
    }
    ((float4*)xout)[idx] = o;
    if (write_bf) {
        uint2 ob;
        ob.x = f2bf(o.x) | (f2bf(o.y) << 16);
        ob.y = f2bf(o.z) | (f2bf(o.w) << 16);
        ((uint2*)xbout)[idx] = ob;
    }
}

extern "C" void kernel_launch(void* const* d_in, const int* in_sizes, int n_in,
                              void* d_out, int out_size, void* d_ws, size_t ws_size,
                              hipStream_t stream) {
    const float* x     = (const float*)d_in[0];
    const int*   ei    = (const int*)d_in[1];
    const float* Wl    = (const float*)d_in[2];
    const float* bl    = (const float*)d_in[3];
    const float* Wr    = (const float*)d_in[4];
    const float* gamma = (const float*)d_in[5];
    const float* beta  = (const float*)d_in[6];
    float* out = (float*)d_out;

    const int N = in_sizes[0] / HH;
    const int E = in_sizes[1] / 2;
    const int MP = ((N + 63) / 64) * 64;
    const int* src = ei;
    const int* dst = ei + E;

    char* p = (char*)d_ws;
    float* cur      = (float*)p;  p += (size_t)MP * HH * 4;
    ushort* aggb    = (ushort*)p; p += (size_t)MP * HH * 2;   // h aliases this (bf16)
    ushort* xb      = (ushort*)p; p += (size_t)MP * HH * 2;
    ushort* Wb      = (ushort*)p; p += (size_t)3 * HH * 256 * 2;
    float* invdeg   = (float*)p;  p += (size_t)N * 4;
    float* stats    = (float*)p;  p += 256 * 4;
    int* cnt        = (int*)p;    p += (size_t)N * 4;
    int* row_ptr    = (int*)p;    p += (size_t)(N + 4) * 4;
    int* pos        = (int*)p;    p += (size_t)N * 4;
    int* bsum       = (int*)p;    p += 256 * 4;
    int* edge_csr   = (int*)p;    p += (size_t)E * 4;

    // ---- CSR build (once) ----
    hipMemsetAsync(cnt, 0, (size_t)N * sizeof(int), stream);
    hist_kernel<<<(E + 255) / 256, 256, 0, stream>>>(dst, cnt, E);
    scan_partial_kernel<<<256, 256, 0, stream>>>(cnt, bsum, N);
    scan_bsum_kernel<<<1, 256, 0, stream>>>(bsum);
    scan_write_kernel<<<256, 256, 0, stream>>>(cnt, bsum, row_ptr, invdeg, pos, N, E);
    fill_kernel<<<(E + 255) / 256, 256, 0, stream>>>(src, dst, pos, edge_csr, E);

    // ---- converts / pad zero (once) ----
    int padElems = (MP - N) * HH;
    if (padElems > 0)
        zero_pad_kernel<<<(padElems + 255) / 256, 256, 0, stream>>>(aggb, xb, N, MP);
    const int wtotal = 3 * HH * 256;
    convert_w_kernel<<<(wtotal + 255) / 256, 256, 0, stream>>>(Wl, Wr, Wb, wtotal);
    const int n4 = N * (HH / 4);
    convert_x_kernel<<<(n4 + 255) / 256, 256, 0, stream>>>(x, xb, n4);

    const int gather_blocks = (N + 15) / 16;
    const int gemm_blocks = MP / 64;
    const int elem_blocks = (n4 + 255) / 256;

    for (int layer = 0; layer < 3; ++layer) {
        hipMemsetAsync(stats, 0, 256 * sizeof(float), stream);

        gather_kernel<<<gather_blocks, 256, 0, stream>>>(
            xb, row_ptr, edge_csr, invdeg, aggb, N);

        mfma_gemm_kernel<<<gemm_blocks, 256, 0, stream>>>(
            aggb, xb, Wb + (size_t)layer * HH * 256,
            bl + (size_t)layer * HH,
            aggb /* hb aliases aggb */, stats, N);

        bn_relu_res_kernel<<<elem_blocks, 256, 0, stream>>>(
            aggb /* hb */, cur,
            stats, gamma + (size_t)layer * HH, beta + (size_t)layer * HH, 1.0f / (float)N,
            (layer == 2) ? out : cur, xb,
            n4, layer > 0 ? 1 : 0, layer < 2 ? 1 : 0);
    }
}

// Round 5
// 323.032 us; speedup vs baseline: 14.5721x; 1.1462x over previous
//
#include <hip/hip_runtime.h>

#define HH 128
#define EPS 1e-5f
#define NBMAX 256     // max buckets (N < 65536 assumed: node ids fit ushort)
#define SCAP 40       // scatter LDS queue capacity per bucket
#define FCAP 12288    // finalize LDS edge capacity per bucket

typedef __bf16 bf16x8 __attribute__((ext_vector_type(8)));
typedef float f32x4 __attribute__((ext_vector_type(4)));

__device__ __forceinline__ unsigned f2bf(float f) {
    unsigned u = __builtin_bit_cast(unsigned, f);
    return (u + 0x7FFFu + ((u >> 16) & 1u)) >> 16;   // RNE
}
__device__ __forceinline__ float bflo(unsigned w) { return __builtin_bit_cast(float, w << 16); }
__device__ __forceinline__ float bfhi(unsigned w) { return __builtin_bit_cast(float, w & 0xFFFF0000u); }

// ---------------- CSR build (bucketed, once) ----------------
// bucket = dst >> 8. Pass 1: bucket histogram (LDS-privatized).
__global__ __launch_bounds__(256) void bucket_hist_kernel(const int* __restrict__ dst,
                                                          int* __restrict__ bcnt, int E) {
    __shared__ int h[NBMAX];
    const int t = threadIdx.x;
    h[t] = 0;
    __syncthreads();
    for (int e = blockIdx.x * 256 + t; e < E; e += gridDim.x * 256)
        atomicAdd(&h[dst[e] >> 8], 1);
    __syncthreads();
    if (h[t]) atomicAdd(&bcnt[t], h[t]);
}

// Pass 2: exclusive scan of bucket counts -> boff[NB+1]; init gpos.
__global__ __launch_bounds__(256) void bucket_scan_kernel(const int* __restrict__ bcnt,
                                                          int* __restrict__ boff,
                                                          int* __restrict__ gpos, int NB, int E) {
    __shared__ int s[NBMAX];
    const int t = threadIdx.x;
    s[t] = (t < NB) ? bcnt[t] : 0;
    __syncthreads();
    for (int off = 1; off < 256; off <<= 1) {
        int u = (t >= off) ? s[t - off] : 0;
        __syncthreads();
        s[t] += u;
        __syncthreads();
    }
    int excl = (t == 0) ? 0 : s[t - 1];
    if (t < NB) { boff[t] = excl; gpos[t] = excl; }
    if (t == 0) boff[NB] = E;
}

// Pass 3: LDS-staged scatter of packed (dst<<16)|src into bucket regions (128-B chunk flushes).
__global__ __launch_bounds__(256) void bucket_scatter_kernel(
    const int* __restrict__ src, const int* __restrict__ dst,
    int* __restrict__ gpos, unsigned* __restrict__ packed, int E, int GRID)
{
    __shared__ unsigned q[NBMAX][SCAP];
    __shared__ int qc[NBMAX];
    const int t = threadIdx.x;
    const int b = blockIdx.x;
    qc[t] = 0;
    __syncthreads();
    const int ebeg = (int)((long)b * E / GRID);
    const int eend = (int)((long)(b + 1) * E / GRID);
    for (int base = ebeg; base < eend; base += 256) {
        int e = base + t;
        if (e < eend) {
            int d = dst[e];
            unsigned pk = ((unsigned)d << 16) | (unsigned)src[e];
            int bk = d >> 8;
            int slot = atomicAdd(&qc[bk], 1);
            if (slot < SCAP) q[bk][slot] = pk;
            else { int p = atomicAdd(&gpos[bk], 1); packed[p] = pk; }   // rare overflow
        }
        __syncthreads();
        // flush phase: thread t owns bucket t
        int c = qc[t]; if (c > SCAP) c = SCAP;
        if (c >= 32) {
            int p = atomicAdd(&gpos[t], 32);
            for (int i = 0; i < 32; ++i) packed[p + i] = q[t][i];
            for (int i = 32; i < c; ++i) q[t][i - 32] = q[t][i];
            qc[t] = c - 32;
        } else {
            qc[t] = c;
        }
        __syncthreads();
    }
    int c = qc[t]; if (c > SCAP) c = SCAP;
    if (c > 0) {
        int p = atomicAdd(&gpos[t], c);
        for (int i = 0; i < c; ++i) packed[p + i] = q[t][i];
    }
}

// Pass 4: per-bucket CSR finalize — row_ptr, invdeg, edge_csr (ushort, coalesced copy-out).
__global__ __launch_bounds__(256) void bucket_finalize_kernel(
    const unsigned* __restrict__ packed, const int* __restrict__ boff,
    int* __restrict__ row_ptr, float* __restrict__ invdeg,
    ushort* __restrict__ edge_csr, int N, int E)
{
    __shared__ int hist[256];
    __shared__ int posq[256];
    __shared__ ushort outq[FCAP];
    const int b = blockIdx.x, t = threadIdx.x;
    const int beg = boff[b], end = boff[b + 1], n = end - beg;
    hist[t] = 0;
    __syncthreads();
    for (int i = beg + t; i < end; i += 256)
        atomicAdd(&hist[(packed[i] >> 16) & 255], 1);
    __syncthreads();
    const int c = hist[t];
    for (int off = 1; off < 256; off <<= 1) {
        int u = (t >= off) ? hist[t - off] : 0;
        __syncthreads();
        hist[t] += u;
        __syncthreads();
    }
    const int excl = hist[t] - c;   // exclusive scan
    const int node = (b << 8) + t;
    if (node < N) {
        row_ptr[node] = beg + excl;
        invdeg[node] = 1.0f / fmaxf((float)c, 1.0f);
    }
    if (b == 0 && t == 0) row_ptr[N] = E;
    posq[t] = excl;
    __syncthreads();
    if (n <= FCAP) {
        for (int i = beg + t; i < end; i += 256) {
            unsigned pk = packed[i];
            int p = atomicAdd(&posq[(pk >> 16) & 255], 1);
            outq[p] = (ushort)(pk & 0xFFFFu);
        }
        __syncthreads();
        for (int i = t; i < n; i += 256) edge_csr[beg + i] = outq[i];
    } else {   // paranoia fallback (never for this dataset)
        for (int i = beg + t; i < end; i += 256) {
            unsigned pk = packed[i];
            int p = atomicAdd(&posq[(pk >> 16) & 255], 1);
            edge_csr[beg + p] = (ushort)(pk & 0xFFFFu);
        }
    }
}

// ---------------- converts ----------------
__global__ void convert_x_kernel(const float* __restrict__ x, ushort* __restrict__ xb, int n4) {
    int idx = blockIdx.x * 256 + threadIdx.x;   // float4 units
    if (idx >= n4) return;
    float4 v = ((const float4*)x)[idx];
    uint2 o;
    o.x = f2bf(v.x) | (f2bf(v.y) << 16);
    o.y = f2bf(v.z) | (f2bf(v.w) << 16);
    ((uint2*)xb)[idx] = o;
}

__global__ void convert_w_kernel(const float* __restrict__ Wl, const float* __restrict__ Wr,
                                 ushort* __restrict__ Wb, int total) {
    int idx = blockIdx.x * 256 + threadIdx.x;
    if (idx >= total) return;
    int l = idx / (HH * 256);
    int rem = idx - l * (HH * 256);
    int col = rem >> 8;
    int k = rem & 255;
    float v = (k < HH) ? Wl[(size_t)l * HH * HH + col * HH + k]
                       : Wr[(size_t)l * HH * HH + col * HH + (k - HH)];
    Wb[idx] = (ushort)f2bf(v);
}

__global__ void zero_pad_kernel(ushort* __restrict__ aggb, ushort* __restrict__ xb,
                                int N, int MP) {
    int i = blockIdx.x * 256 + threadIdx.x;
    int total = (MP - N) * HH;
    if (i < total) {
        aggb[(size_t)N * HH + i] = 0;
        xb[(size_t)N * HH + i] = 0;
    }
}

// ---------------- gather (bf16 in, f32 accum, bf16 out) ----------------
__global__ __launch_bounds__(256) void gather_kernel(
    const ushort* __restrict__ xb, const int* __restrict__ row_ptr,
    const ushort* __restrict__ edge_csr, const float* __restrict__ invdeg,
    ushort* __restrict__ aggb, int N)
{
    const int node = blockIdx.x * 16 + (threadIdx.x >> 4);
    if (node >= N) return;
    const int l16 = threadIdx.x & 15;
    const int beg = row_ptr[node], end = row_ptr[node + 1];
    float a0=0,a1=0,a2=0,a3=0,a4=0,a5=0,a6=0,a7=0;
    int e = beg;
    for (; e + 1 < end; e += 2) {
        int s0 = edge_csr[e], s1 = edge_csr[e + 1];
        uint4 v0 = *(const uint4*)(xb + (size_t)s0 * HH + l16 * 8);
        uint4 v1 = *(const uint4*)(xb + (size_t)s1 * HH + l16 * 8);
        a0 += bflo(v0.x) + bflo(v1.x);  a1 += bfhi(v0.x) + bfhi(v1.x);
        a2 += bflo(v0.y) + bflo(v1.y);  a3 += bfhi(v0.y) + bfhi(v1.y);
        a4 += bflo(v0.z) + bflo(v1.z);  a5 += bfhi(v0.z) + bfhi(v1.z);
        a6 += bflo(v0.w) + bflo(v1.w);  a7 += bfhi(v0.w) + bfhi(v1.w);
    }
    if (e < end) {
        int s0 = edge_csr[e];
        uint4 v0 = *(const uint4*)(xb + (size_t)s0 * HH + l16 * 8);
        a0 += bflo(v0.x); a1 += bfhi(v0.x);
        a2 += bflo(v0.y); a3 += bfhi(v0.y);
        a4 += bflo(v0.z); a5 += bfhi(v0.z);
        a6 += bflo(v0.w); a7 += bfhi(v0.w);
    }
    const float id = invdeg[node];
    uint4 o;
    o.x = f2bf(a0 * id) | (f2bf(a1 * id) << 16);
    o.y = f2bf(a2 * id) | (f2bf(a3 * id) << 16);
    o.z = f2bf(a4 * id) | (f2bf(a5 * id) << 16);
    o.w = f2bf(a6 * id) | (f2bf(a7 * id) << 16);
    *(uint4*)(aggb + (size_t)node * HH + l16 * 8) = o;
}

// ---------------- MFMA GEMM: h = [agg|x] @ [Wl|Wr]^T + bl, fused BN stats ----------------
__global__ __launch_bounds__(256) void mfma_gemm_kernel(
    const ushort* __restrict__ aggb, const ushort* __restrict__ xb,
    const ushort* __restrict__ Wb, const float* __restrict__ bl,
    ushort* __restrict__ hb, float* __restrict__ stats, int N)
{
    const int tid = threadIdx.x;
    const int lane = tid & 63;
    const int wave = tid >> 6;
    const int m0 = blockIdx.x * 64;
    const int l15 = lane & 15;
    const int lg = lane >> 4;
    const int colbase = wave * 32;

    bf16x8 bfr[8][2];
#pragma unroll
    for (int s = 0; s < 8; ++s)
#pragma unroll
        for (int ct = 0; ct < 2; ++ct) {
            int col = colbase + ct * 16 + l15;
            bfr[s][ct] = *(const bf16x8*)(Wb + (size_t)col * 256 + s * 32 + lg * 8);
        }

    f32x4 acc[4][2];
#pragma unroll
    for (int rt = 0; rt < 4; ++rt)
#pragma unroll
        for (int ct = 0; ct < 2; ++ct)
            acc[rt][ct] = (f32x4){0.f, 0.f, 0.f, 0.f};

#pragma unroll
    for (int s = 0; s < 8; ++s) {
        const ushort* Abase = (s < 4) ? aggb : xb;
        const int ks = (s & 3) * 32;
#pragma unroll
        for (int rt = 0; rt < 4; ++rt) {
            int row = m0 + rt * 16 + l15;
            bf16x8 a = *(const bf16x8*)(Abase + (size_t)row * HH + ks + lg * 8);
#pragma unroll
            for (int ct = 0; ct < 2; ++ct)
                acc[rt][ct] = __builtin_amdgcn_mfma_f32_16x16x32_bf16(a, bfr[s][ct], acc[rt][ct], 0, 0, 0);
        }
    }

    __shared__ float s_sum[128];
    __shared__ float s_sum2[128];
    if (tid < 128) { s_sum[tid] = 0.f; s_sum2[tid] = 0.f; }
    __syncthreads();

#pragma unroll
    for (int ct = 0; ct < 2; ++ct) {
        const int col = colbase + ct * 16 + l15;
        const float bias = bl[col];
        float s1 = 0.f, s2 = 0.f;
#pragma unroll
        for (int rt = 0; rt < 4; ++rt) {
#pragma unroll
            for (int r = 0; r < 4; ++r) {
                int row = m0 + rt * 16 + lg * 4 + r;
                float v = acc[rt][ct][r] + bias;
                if (row < N) {
                    hb[(size_t)row * HH + col] = (ushort)f2bf(v);
                    s1 += v;
                    s2 += v * v;
                }
            }
        }
        atomicAdd(&s_sum[col], s1);
        atomicAdd(&s_sum2[col], s2);
    }
    __syncthreads();
    if (tid < 128) {
        atomicAdd(&stats[tid], s_sum[tid]);
        atomicAdd(&stats[128 + tid], s_sum2[tid]);
    }
}

// ---------------- normalize + relu + residual (bf16 chain; finalize fused) ----------------
__global__ __launch_bounds__(256) void bn_relu_res_kernel(
    const ushort* __restrict__ hb, const float* __restrict__ stats,
    const float* __restrict__ gamma, const float* __restrict__ beta, float invN,
    ushort* __restrict__ xb, float* __restrict__ outf,
    int n4, int residual, int final_layer)
{
    __shared__ float s_ab[256];
    const int t = threadIdx.x;
    if (t < 128) {
        float mean = stats[t] * invN;
        float var = stats[128 + t] * invN - mean * mean;
        float istd = rsqrtf(var + EPS);
        float a = gamma[t] * istd;
        s_ab[t] = a;
        s_ab[128 + t] = beta[t] - mean * a;
    }
    __syncthreads();
    int idx = blockIdx.x * 256 + t;   // uint2 (4 bf16) units over N*32
    if (idx >= n4) return;
    int f4 = idx & 31;
    uint2 hw = ((const uint2*)hb)[idx];
    float4 h4 = make_float4(bflo(hw.x), bfhi(hw.x), bflo(hw.y), bfhi(hw.y));
    float4 a4 = *(const float4*)&s_ab[f4 * 4];
    float4 b4 = *(const float4*)&s_ab[128 + f4 * 4];
    float4 o;
    o.x = fmaxf(fmaf(h4.x, a4.x, b4.x), 0.f);
    o.y = fmaxf(fmaf(h4.y, a4.y, b4.y), 0.f);
    o.z = fmaxf(fmaf(h4.z, a4.z, b4.z), 0.f);
    o.w = fmaxf(fmaf(h4.w, a4.w, b4.w), 0.f);
    if (residual) {
        uint2 xw = ((const uint2*)xb)[idx];
        o.x += bflo(xw.x); o.y += bfhi(xw.x);
        o.z += bflo(xw.y); o.w += bfhi(xw.y);
    }
    if (final_layer) {
        ((float4*)outf)[idx] = o;
    } else {
        uint2 ob;
        ob.x = f2bf(o.x) | (f2bf(o.y) << 16);
        ob.y = f2bf(o.z) | (f2bf(o.w) << 16);
        ((uint2*)xb)[idx] = ob;
    }
}

extern "C" void kernel_launch(void* const* d_in, const int* in_sizes, int n_in,
                              void* d_out, int out_size, void* d_ws, size_t ws_size,
                              hipStream_t stream) {
    const float* x     = (const float*)d_in[0];
    const int*   ei    = (const int*)d_in[1];
    const float* Wl    = (const float*)d_in[2];
    const float* bl    = (const float*)d_in[3];
    const float* Wr    = (const float*)d_in[4];
    const float* gamma = (const float*)d_in[5];
    const float* beta  = (const float*)d_in[6];
    float* out = (float*)d_out;

    const int N = in_sizes[0] / HH;           // 50000 (< 65536: ushort node ids)
    const int E = in_sizes[1] / 2;
    const int MP = ((N + 63) / 64) * 64;
    const int NB = (N + 255) >> 8;            // buckets
    const int* src = ei;
    const int* dst = ei + E;

    char* p = (char*)d_ws;
    ushort* aggb    = (ushort*)p; p += (size_t)MP * HH * 2;   // h aliases this (bf16)
    ushort* xb      = (ushort*)p; p += (size_t)MP * HH * 2;
    ushort* Wb      = (ushort*)p; p += (size_t)3 * HH * 256 * 2;
    float* invdeg   = (float*)p;  p += (size_t)N * 4;
    float* stats3   = (float*)p;  p += 768 * 4;
    int* row_ptr    = (int*)p;    p += (size_t)(N + 4) * 4;
    int* bcnt       = (int*)p;    p += NBMAX * 4;
    int* boff       = (int*)p;    p += (NBMAX + 1) * 4;
    int* gpos       = (int*)p;    p += NBMAX * 4;
    unsigned* packed = (unsigned*)p; p += (size_t)E * 4;
    ushort* edge_csr = (ushort*)p;  p += (size_t)((E + 7) & ~7) * 2;

    // ---- CSR build (bucketed, once) ----
    hipMemsetAsync(bcnt, 0, NBMAX * sizeof(int), stream);
    hipMemsetAsync(stats3, 0, 768 * sizeof(float), stream);
    bucket_hist_kernel<<<512, 256, 0, stream>>>(dst, bcnt, E);
    bucket_scan_kernel<<<1, 256, 0, stream>>>(bcnt, boff, gpos, NB, E);
    bucket_scatter_kernel<<<128, 256, 0, stream>>>(src, dst, gpos, packed, E, 128);
    bucket_finalize_kernel<<<NB, 256, 0, stream>>>(packed, boff, row_ptr, invdeg, edge_csr, N, E);

    // ---- converts / pad (once) ----
    int padElems = (MP - N) * HH;
    if (padElems > 0)
        zero_pad_kernel<<<(padElems + 255) / 256, 256, 0, stream>>>(aggb, xb, N, MP);
    const int wtotal = 3 * HH * 256;
    convert_w_kernel<<<(wtotal + 255) / 256, 256, 0, stream>>>(Wl, Wr, Wb, wtotal);
    const int n4 = N * (HH / 4);
    convert_x_kernel<<<(n4 + 255) / 256, 256, 0, stream>>>(x, xb, n4);

    const int gather_blocks = (N + 15) / 16;
    const int gemm_blocks = MP / 64;
    const int elem_blocks = (n4 + 255) / 256;

    for (int layer = 0; layer < 3; ++layer) {
        float* stats = stats3 + layer * 256;

        gather_kernel<<<gather_blocks, 256, 0, stream>>>(
            xb, row_ptr, edge_csr, invdeg, aggb, N);

        mfma_gemm_kernel<<<gemm_blocks, 256, 0, stream>>>(
            aggb, xb, Wb + (size_t)layer * HH * 256,
            bl + (size_t)layer * HH,
            aggb /* hb aliases aggb */, stats, N);

        bn_relu_res_kernel<<<elem_blocks, 256, 0, stream>>>(
            aggb /* hb */, stats,
            gamma + (size_t)layer * HH, beta + (size_t)layer * HH, 1.0f / (float)N,
            xb, out, n4, layer > 0 ? 1 : 0, layer == 2 ? 1 : 0);
    }
}

// Round 6
// 292.930 us; speedup vs baseline: 16.0695x; 1.1028x over previous
//
#include <hip/hip_runtime.h>

#define HH 128
#define EPS 1e-5f
#define NBMAX 256     // max buckets (N < 65536 assumed: node ids fit ushort)
#define SCAP 40       // scatter LDS queue capacity per bucket
#define FCAP 12288    // finalize LDS edge capacity per bucket

typedef __bf16 bf16x8 __attribute__((ext_vector_type(8)));
typedef float f32x4 __attribute__((ext_vector_type(4)));

__device__ __forceinline__ unsigned f2bf(float f) {
    unsigned u = __builtin_bit_cast(unsigned, f);
    return (u + 0x7FFFu + ((u >> 16) & 1u)) >> 16;   // RNE
}
__device__ __forceinline__ float bflo(unsigned w) { return __builtin_bit_cast(float, w << 16); }
__device__ __forceinline__ float bfhi(unsigned w) { return __builtin_bit_cast(float, w & 0xFFFF0000u); }

__device__ __forceinline__ void gload_lds16(const void* g, void* l) {
    __builtin_amdgcn_global_load_lds(
        (const __attribute__((address_space(1))) unsigned int*)g,
        (__attribute__((address_space(3))) unsigned int*)l,
        16, 0, 0);
}

// ---------------- CSR build (bucketed, once) ----------------
__global__ __launch_bounds__(256) void bucket_hist_kernel(const int* __restrict__ dst,
                                                          int* __restrict__ bcnt, int E) {
    __shared__ int h[NBMAX];
    const int t = threadIdx.x;
    h[t] = 0;
    __syncthreads();
    for (int e = blockIdx.x * 256 + t; e < E; e += gridDim.x * 256)
        atomicAdd(&h[dst[e] >> 8], 1);
    __syncthreads();
    if (h[t]) atomicAdd(&bcnt[t], h[t]);
}

__global__ __launch_bounds__(256) void bucket_scan_kernel(const int* __restrict__ bcnt,
                                                          int* __restrict__ boff,
                                                          int* __restrict__ gpos, int NB, int E) {
    __shared__ int s[NBMAX];
    const int t = threadIdx.x;
    s[t] = (t < NB) ? bcnt[t] : 0;
    __syncthreads();
    for (int off = 1; off < 256; off <<= 1) {
        int u = (t >= off) ? s[t - off] : 0;
        __syncthreads();
        s[t] += u;
        __syncthreads();
    }
    int excl = (t == 0) ? 0 : s[t - 1];
    if (t < NB) { boff[t] = excl; gpos[t] = excl; }
    if (t == 0) boff[NB] = E;
}

__global__ __launch_bounds__(256) void bucket_scatter_kernel(
    const int* __restrict__ src, const int* __restrict__ dst,
    int* __restrict__ gpos, unsigned* __restrict__ packed, int E, int GRID)
{
    __shared__ unsigned q[NBMAX][SCAP];
    __shared__ int qc[NBMAX];
    const int t = threadIdx.x;
    const int b = blockIdx.x;
    qc[t] = 0;
    __syncthreads();
    const int ebeg = (int)((long)b * E / GRID);
    const int eend = (int)((long)(b + 1) * E / GRID);
    for (int base = ebeg; base < eend; base += 256) {
        int e = base + t;
        if (e < eend) {
            int d = dst[e];
            unsigned pk = ((unsigned)d << 16) | (unsigned)src[e];
            int bk = d >> 8;
            int slot = atomicAdd(&qc[bk], 1);
            if (slot < SCAP) q[bk][slot] = pk;
            else { int p = atomicAdd(&gpos[bk], 1); packed[p] = pk; }
        }
        __syncthreads();
        int c = qc[t]; if (c > SCAP) c = SCAP;
        if (c >= 32) {
            int p = atomicAdd(&gpos[t], 32);
            for (int i = 0; i < 32; ++i) packed[p + i] = q[t][i];
            for (int i = 32; i < c; ++i) q[t][i - 32] = q[t][i];
            qc[t] = c - 32;
        } else {
            qc[t] = c;
        }
        __syncthreads();
    }
    int c = qc[t]; if (c > SCAP) c = SCAP;
    if (c > 0) {
        int p = atomicAdd(&gpos[t], c);
        for (int i = 0; i < c; ++i) packed[p + i] = q[t][i];
    }
}

__global__ __launch_bounds__(256) void bucket_finalize_kernel(
    const unsigned* __restrict__ packed, const int* __restrict__ boff,
    int* __restrict__ row_ptr, float* __restrict__ invdeg,
    ushort* __restrict__ edge_csr, int N, int E)
{
    __shared__ int hist[256];
    __shared__ int posq[256];
    __shared__ ushort outq[FCAP];
    const int b = blockIdx.x, t = threadIdx.x;
    const int beg = boff[b], end = boff[b + 1], n = end - beg;
    hist[t] = 0;
    __syncthreads();
    for (int i = beg + t; i < end; i += 256)
        atomicAdd(&hist[(packed[i] >> 16) & 255], 1);
    __syncthreads();
    const int c = hist[t];
    for (int off = 1; off < 256; off <<= 1) {
        int u = (t >= off) ? hist[t - off] : 0;
        __syncthreads();
        hist[t] += u;
        __syncthreads();
    }
    const int excl = hist[t] - c;
    const int node = (b << 8) + t;
    if (node < N) {
        row_ptr[node] = beg + excl;
        invdeg[node] = 1.0f / fmaxf((float)c, 1.0f);
    }
    if (b == 0 && t == 0) row_ptr[N] = E;
    posq[t] = excl;
    __syncthreads();
    if (n <= FCAP) {
        for (int i = beg + t; i < end; i += 256) {
            unsigned pk = packed[i];
            int p = atomicAdd(&posq[(pk >> 16) & 255], 1);
            outq[p] = (ushort)(pk & 0xFFFFu);
        }
        __syncthreads();
        for (int i = t; i < n; i += 256) edge_csr[beg + i] = outq[i];
    } else {
        for (int i = beg + t; i < end; i += 256) {
            unsigned pk = packed[i];
            int p = atomicAdd(&posq[(pk >> 16) & 255], 1);
            edge_csr[beg + p] = (ushort)(pk & 0xFFFFu);
        }
    }
}

// ---------------- converts ----------------
__global__ void convert_x_kernel(const float* __restrict__ x, ushort* __restrict__ xb, int n4) {
    int idx = blockIdx.x * 256 + threadIdx.x;
    if (idx >= n4) return;
    float4 v = ((const float4*)x)[idx];
    uint2 o;
    o.x = f2bf(v.x) | (f2bf(v.y) << 16);
    o.y = f2bf(v.z) | (f2bf(v.w) << 16);
    ((uint2*)xb)[idx] = o;
}

__global__ void convert_w_kernel(const float* __restrict__ Wl, const float* __restrict__ Wr,
                                 ushort* __restrict__ Wb, int total) {
    int idx = blockIdx.x * 256 + threadIdx.x;
    if (idx >= total) return;
    int l = idx / (HH * 256);
    int rem = idx - l * (HH * 256);
    int col = rem >> 8;
    int k = rem & 255;
    float v = (k < HH) ? Wl[(size_t)l * HH * HH + col * HH + k]
                       : Wr[(size_t)l * HH * HH + col * HH + (k - HH)];
    Wb[idx] = (ushort)f2bf(v);
}

__global__ void zero_pad_kernel(ushort* __restrict__ aggb, ushort* __restrict__ xb,
                                int N, int MP) {
    int i = blockIdx.x * 256 + threadIdx.x;
    int total = (MP - N) * HH;
    if (i < total) {
        aggb[(size_t)N * HH + i] = 0;
        xb[(size_t)N * HH + i] = 0;
    }
}

// ---------------- gather (bf16 in, f32 accum, bf16 out) ----------------
__global__ __launch_bounds__(256) void gather_kernel(
    const ushort* __restrict__ xb, const int* __restrict__ row_ptr,
    const ushort* __restrict__ edge_csr, const float* __restrict__ invdeg,
    ushort* __restrict__ aggb, int N)
{
    const int node = blockIdx.x * 16 + (threadIdx.x >> 4);
    if (node >= N) return;
    const int l16 = threadIdx.x & 15;
    const int beg = row_ptr[node], end = row_ptr[node + 1];
    float a0=0,a1=0,a2=0,a3=0,a4=0,a5=0,a6=0,a7=0;
    int e = beg;
    for (; e + 1 < end; e += 2) {
        int s0 = edge_csr[e], s1 = edge_csr[e + 1];
        uint4 v0 = *(const uint4*)(xb + (size_t)s0 * HH + l16 * 8);
        uint4 v1 = *(const uint4*)(xb + (size_t)s1 * HH + l16 * 8);
        a0 += bflo(v0.x) + bflo(v1.x);  a1 += bfhi(v0.x) + bfhi(v1.x);
        a2 += bflo(v0.y) + bflo(v1.y);  a3 += bfhi(v0.y) + bfhi(v1.y);
        a4 += bflo(v0.z) + bflo(v1.z);  a5 += bfhi(v0.z) + bfhi(v1.z);
        a6 += bflo(v0.w) + bflo(v1.w);  a7 += bfhi(v0.w) + bfhi(v1.w);
    }
    if (e < end) {
        int s0 = edge_csr[e];
        uint4 v0 = *(const uint4*)(xb + (size_t)s0 * HH + l16 * 8);
        a0 += bflo(v0.x); a1 += bfhi(v0.x);
        a2 += bflo(v0.y); a3 += bfhi(v0.y);
        a4 += bflo(v0.z); a5 += bfhi(v0.z);
        a6 += bflo(v0.w); a7 += bfhi(v0.w);
    }
    const float id = invdeg[node];
    uint4 o;
    o.x = f2bf(a0 * id) | (f2bf(a1 * id) << 16);
    o.y = f2bf(a2 * id) | (f2bf(a3 * id) << 16);
    o.z = f2bf(a4 * id) | (f2bf(a5 * id) << 16);
    o.w = f2bf(a6 * id) | (f2bf(a7 * id) << 16);
    *(uint4*)(aggb + (size_t)node * HH + l16 * 8) = o;
}

// ---------------- MFMA GEMM: h = [agg|x] @ [Wl|Wr]^T + bl, fused BN stats ----------------
// A-tile (64 rows x 256 k bf16 = 32 KB) staged to LDS via global_load_lds width=16
// with XOR chunk-swizzle (on the GLOBAL source; LDS dest linear — m104) and the same
// XOR on ds_read_b128 (involution). B-frags in VGPRs. One barrier, then 64 MFMAs/wave.
__global__ __launch_bounds__(256) void mfma_gemm_kernel(
    const ushort* __restrict__ aggb, const ushort* __restrict__ xb,
    const ushort* __restrict__ Wb, const float* __restrict__ bl,
    ushort* __restrict__ hb, float* __restrict__ stats, int N)
{
    __shared__ ushort As[64 * 256];    // [row][256 k], 16B-chunk swizzled within row; 32 KB
    __shared__ float s_sum[128];
    __shared__ float s_sum2[128];

    const int tid = threadIdx.x;
    const int lane = tid & 63;
    const int wave = tid >> 6;
    const int m0 = blockIdx.x * 64;
    const int l15 = lane & 15;
    const int lg = lane >> 4;
    const int colbase = wave * 32;

    // B preload: 2 col-tiles x 8 k-steps (64 VGPRs); L2-resident, every block reads same 64 KB
    bf16x8 bfr[8][2];
#pragma unroll
    for (int s = 0; s < 8; ++s)
#pragma unroll
        for (int ct = 0; ct < 2; ++ct) {
            int col = colbase + ct * 16 + l15;
            bfr[s][ct] = *(const bf16x8*)(Wb + (size_t)col * 256 + s * 32 + lg * 8);
        }

    // stage A: 2048 16B-chunks; wave issues 8 x (64 lanes x 16B), dest = uniform base + lane*16
#pragma unroll
    for (int i = 0; i < 8; ++i) {
        const int cb = (i * 4 + wave) * 64;          // wave-uniform chunk base
        const int L = cb + lane;                     // this lane's linear chunk
        const int r = L >> 5;                        // row 0..63
        const int c = L & 31;                        // lds chunk within row
        const int cs = (c & 0x18) | ((c & 7) ^ (r & 7));   // swizzled source chunk
        const ushort* gsrc = (cs < 16)
            ? (aggb + (size_t)(m0 + r) * HH + cs * 8)
            : (xb   + (size_t)(m0 + r) * HH + (cs - 16) * 8);
        gload_lds16(gsrc, &As[(size_t)cb * 8]);
    }

    if (tid < 128) { s_sum[tid] = 0.f; s_sum2[tid] = 0.f; }

    f32x4 acc[4][2];
#pragma unroll
    for (int rt = 0; rt < 4; ++rt)
#pragma unroll
        for (int ct = 0; ct < 2; ++ct)
            acc[rt][ct] = (f32x4){0.f, 0.f, 0.f, 0.f};

    __syncthreads();   // drains vmcnt (global_load_lds) before LDS reads

#pragma unroll
    for (int s = 0; s < 8; ++s) {
#pragma unroll
        for (int rt = 0; rt < 4; ++rt) {
            const int r = rt * 16 + l15;
            const int g = s * 4 + lg;                          // global chunk 0..31
            const int c = (g & 0x18) | ((g & 7) ^ (r & 7));    // same involution
            bf16x8 a = *(const bf16x8*)&As[r * 256 + c * 8];
#pragma unroll
            for (int ct = 0; ct < 2; ++ct)
                acc[rt][ct] = __builtin_amdgcn_mfma_f32_16x16x32_bf16(a, bfr[s][ct], acc[rt][ct], 0, 0, 0);
        }
    }

#pragma unroll
    for (int ct = 0; ct < 2; ++ct) {
        const int col = colbase + ct * 16 + l15;
        const float bias = bl[col];
        float s1 = 0.f, s2 = 0.f;
#pragma unroll
        for (int rt = 0; rt < 4; ++rt) {
#pragma unroll
            for (int r = 0; r < 4; ++r) {
                int row = m0 + rt * 16 + lg * 4 + r;
                float v = acc[rt][ct][r] + bias;
                if (row < N) {
                    hb[(size_t)row * HH + col] = (ushort)f2bf(v);
                    s1 += v;
                    s2 += v * v;
                }
            }
        }
        atomicAdd(&s_sum[col], s1);
        atomicAdd(&s_sum2[col], s2);
    }
    __syncthreads();
    if (tid < 128) {
        atomicAdd(&stats[tid], s_sum[tid]);
        atomicAdd(&stats[128 + tid], s_sum2[tid]);
    }
}

// ---------------- normalize + relu + residual (bf16 chain; finalize fused) ----------------
__global__ __launch_bounds__(256) void bn_relu_res_kernel(
    const ushort* __restrict__ hb, const float* __restrict__ stats,
    const float* __restrict__ gamma, const float* __restrict__ beta, float invN,
    ushort* __restrict__ xb, float* __restrict__ outf,
    int n4, int residual, int final_layer)
{
    __shared__ float s_ab[256];
    const int t = threadIdx.x;
    if (t < 128) {
        float mean = stats[t] * invN;
        float var = stats[128 + t] * invN - mean * mean;
        float istd = rsqrtf(var + EPS);
        float a = gamma[t] * istd;
        s_ab[t] = a;
        s_ab[128 + t] = beta[t] - mean * a;
    }
    __syncthreads();
    int idx = blockIdx.x * 256 + t;
    if (idx >= n4) return;
    int f4 = idx & 31;
    uint2 hw = ((const uint2*)hb)[idx];
    float4 h4 = make_float4(bflo(hw.x), bfhi(hw.x), bflo(hw.y), bfhi(hw.y));
    float4 a4 = *(const float4*)&s_ab[f4 * 4];
    float4 b4 = *(const float4*)&s_ab[128 + f4 * 4];
    float4 o;
    o.x = fmaxf(fmaf(h4.x, a4.x, b4.x), 0.f);
    o.y = fmaxf(fmaf(h4.y, a4.y, b4.y), 0.f);
    o.z = fmaxf(fmaf(h4.z, a4.z, b4.z), 0.f);
    o.w = fmaxf(fmaf(h4.w, a4.w, b4.w), 0.f);
    if (residual) {
        uint2 xw = ((const uint2*)xb)[idx];
        o.x += bflo(xw.x); o.y += bfhi(xw.x);
        o.z += bflo(xw.y); o.w += bfhi(xw.y);
    }
    if (final_layer) {
        ((float4*)outf)[idx] = o;
    } else {
        uint2 ob;
        ob.x = f2bf(o.x) | (f2bf(o.y) << 16);
        ob.y = f2bf(o.z) | (f2bf(o.w) << 16);
        ((uint2*)xb)[idx] = ob;
    }
}

extern "C" void kernel_launch(void* const* d_in, const int* in_sizes, int n_in,
                              void* d_out, int out_size, void* d_ws, size_t ws_size,
                              hipStream_t stream) {
    const float* x     = (const float*)d_in[0];
    const int*   ei    = (const int*)d_in[1];
    const float* Wl    = (const float*)d_in[2];
    const float* bl    = (const float*)d_in[3];
    const float* Wr    = (const float*)d_in[4];
    const float* gamma = (const float*)d_in[5];
    const float* beta  = (const float*)d_in[6];
    float* out = (float*)d_out;

    const int N = in_sizes[0] / HH;           // 50000 (< 65536: ushort node ids)
    const int E = in_sizes[1] / 2;
    const int MP = ((N + 63) / 64) * 64;
    const int NB = (N + 255) >> 8;
    const int* src = ei;
    const int* dst = ei + E;

    char* p = (char*)d_ws;
    ushort* aggb    = (ushort*)p; p += (size_t)MP * HH * 2;   // h aliases this (bf16)
    ushort* xb      = (ushort*)p; p += (size_t)MP * HH * 2;
    ushort* Wb      = (ushort*)p; p += (size_t)3 * HH * 256 * 2;
    float* invdeg   = (float*)p;  p += (size_t)N * 4;
    float* stats3   = (float*)p;  p += 768 * 4;
    int* row_ptr    = (int*)p;    p += (size_t)(N + 4) * 4;
    int* bcnt       = (int*)p;    p += NBMAX * 4;
    int* boff       = (int*)p;    p += (NBMAX + 1) * 4;
    int* gpos       = (int*)p;    p += NBMAX * 4;
    unsigned* packed = (unsigned*)p; p += (size_t)E * 4;
    ushort* edge_csr = (ushort*)p;  p += (size_t)((E + 7) & ~7) * 2;

    // ---- CSR build (bucketed, once) ----
    hipMemsetAsync(bcnt, 0, NBMAX * sizeof(int), stream);
    hipMemsetAsync(stats3, 0, 768 * sizeof(float), stream);
    bucket_hist_kernel<<<512, 256, 0, stream>>>(dst, bcnt, E);
    bucket_scan_kernel<<<1, 256, 0, stream>>>(bcnt, boff, gpos, NB, E);
    bucket_scatter_kernel<<<128, 256, 0, stream>>>(src, dst, gpos, packed, E, 128);
    bucket_finalize_kernel<<<NB, 256, 0, stream>>>(packed, boff, row_ptr, invdeg, edge_csr, N, E);

    // ---- converts / pad (once) ----
    int padElems = (MP - N) * HH;
    if (padElems > 0)
        zero_pad_kernel<<<(padElems + 255) / 256, 256, 0, stream>>>(aggb, xb, N, MP);
    const int wtotal = 3 * HH * 256;
    convert_w_kernel<<<(wtotal + 255) / 256, 256, 0, stream>>>(Wl, Wr, Wb, wtotal);
    const int n4 = N * (HH / 4);
    convert_x_kernel<<<(n4 + 255) / 256, 256, 0, stream>>>(x, xb, n4);

    const int gather_blocks = (N + 15) / 16;
    const int gemm_blocks = MP / 64;
    const int elem_blocks = (n4 + 255) / 256;

    for (int layer = 0; layer < 3; ++layer) {
        float* stats = stats3 + layer * 256;

        gather_kernel<<<gather_blocks, 256, 0, stream>>>(
            xb, row_ptr, edge_csr, invdeg, aggb, N);

        mfma_gemm_kernel<<<gemm_blocks, 256, 0, stream>>>(
            aggb, xb, Wb + (size_t)layer * HH * 256,
            bl + (size_t)layer * HH,
            aggb /* hb aliases aggb */, stats, N);

        bn_relu_res_kernel<<<elem_blocks, 256, 0, stream>>>(
            aggb /* hb */, stats,
            gamma + (size_t)layer * HH, beta + (size_t)layer * HH, 1.0f / (float)N,
            xb, out, n4, layer > 0 ? 1 : 0, layer == 2 ? 1 : 0);
    }
}